// Round 1
// baseline (49695.166 us; speedup 1.0000x reference)
//
#include <hip/hip_runtime.h>
#include <math.h>

// ---------------- problem constants ----------------
#define NTRK   1500
#define BSZ    64
#define NTOT   (NTRK*BSZ)        // 96000 tracks
#define LHID   128               // lstm hidden
#define TSTEPS 6
#define HID    256               // mlp hidden / output
#define W0PAD  132               // padded mlp_w0 row: [0, w[0..2], w[3..130]]

#define BTILE  16                // tracks per block
#define TPB    256               // 16 threads per track

// output layout (flat fp32, concatenated in return order)
#define OUT1_OFF ((size_t)NTOT*HID)                       // pos_encoding
#define OUT2_OFF (OUT1_OFF + (size_t)NTOT*(HID/2))        // logpt
#define OUT3_OFF (OUT2_OFF + (size_t)NTOT)                // eta
#define OUT4_OFF (OUT3_OFF + (size_t)NTOT)                // phi

__device__ __forceinline__ float sigf(float x) { return 1.0f / (1.0f + __expf(-x)); }

// Re-pad mlp_w0 [256,131] -> [256,132] with a leading zero per row so the
// 128-long hidden part starts at a 16B-aligned offset (4 floats in).
__global__ __launch_bounds__(TPB)
void padw0_kernel(const float* __restrict__ w0, float* __restrict__ w0p)
{
    int idx = blockIdx.x * TPB + threadIdx.x;
    if (idx >= HID * W0PAD) return;
    int n = idx / W0PAD, k = idx - n * W0PAD;
    w0p[idx] = (k >= 1) ? w0[n * 131 + (k - 1)] : 0.0f;
}

// acc[q][jj] += sum_k hrow[k] * W[(q*128 + jb + jj)*128 + k]
__device__ __forceinline__ void accum_mat(float (&acc)[4][8],
                                          const float* __restrict__ W,
                                          const float (&hrow)[LHID + 4],
                                          int jb)
{
    for (int k = 0; k < LHID; k += 4) {
        const float4 hv = *(const float4*)&hrow[k];
        #pragma unroll
        for (int q = 0; q < 4; ++q) {
            #pragma unroll
            for (int jj = 0; jj < 8; ++jj) {
                const float4 w = *(const float4*)&W[(q * LHID + jb + jj) * LHID + k];
                acc[q][jj] += hv.x * w.x + hv.y * w.y + hv.z * w.z + hv.w * w.w;
            }
        }
    }
}

__global__ __launch_bounds__(TPB)
void lstm_mlp_kernel(const float* __restrict__ tfeat,
                     const float* __restrict__ Wih0, const float* __restrict__ Whh0,
                     const float* __restrict__ bih0, const float* __restrict__ bhh0,
                     const float* __restrict__ Wih1, const float* __restrict__ Whh1,
                     const float* __restrict__ bih1, const float* __restrict__ bhh1,
                     const float* __restrict__ w0p, const float* __restrict__ b0,
                     const float* __restrict__ w1,  const float* __restrict__ b1,
                     float* __restrict__ out)
{
    __shared__ float h0[BTILE][LHID + 4];   // layer-0 hidden (padded: 132*4B stride, 16B aligned)
    __shared__ float h1[BTILE][LHID + 4];   // layer-1 hidden
    __shared__ float xb[BTILE][12];         // traj features 6..17
    __shared__ float f3[BTILE][4];          // tf features 0..2
    __shared__ float mh[BTILE][HID + 4];    // mlp hidden (relu output)

    const int tid  = threadIdx.x;
    const int trk  = tid >> 4;      // 0..15  local track
    const int s    = tid & 15;      // 0..15  hidden-slice slot
    const int jb   = s << 3;        // hidden base index (8 per thread)
    const int base = blockIdx.x * BTILE;

    // ---- stage per-track inputs (f-major for coalescing across tracks) ----
    for (int idx = tid; idx < BTILE * 12; idx += TPB) {
        int tl = idx & (BTILE - 1), f = idx >> 4;
        int n = base + tl, b = n / NTRK, tt = n - b * NTRK;
        xb[tl][f] = tfeat[((size_t)(b * 18 + 6 + f)) * NTRK + tt];
    }
    for (int idx = tid; idx < BTILE * 3; idx += TPB) {
        int tl = idx & (BTILE - 1), f = idx >> 4;
        int n = base + tl, b = n / NTRK, tt = n - b * NTRK;
        f3[tl][f] = tfeat[((size_t)(b * 18 + f)) * NTRK + tt];
    }
    for (int idx = tid; idx < BTILE * (LHID + 4); idx += TPB) {
        (&h0[0][0])[idx] = 0.0f;
        (&h1[0][0])[idx] = 0.0f;
    }
    __syncthreads();

    float c0r[8], c1r[8];
    #pragma unroll
    for (int jj = 0; jj < 8; ++jj) { c0r[jj] = 0.0f; c1r[jj] = 0.0f; }

    for (int t = 0; t < TSTEPS; ++t) {
        float acc[4][8];

        // ---------- layer 0: gates = x@Wih0^T + h0@Whh0^T + b ----------
        {
            const float x0 = xb[trk][2 * t], x1 = xb[trk][2 * t + 1];
            #pragma unroll
            for (int q = 0; q < 4; ++q)
                #pragma unroll
                for (int jj = 0; jj < 8; ++jj) {
                    const int r = q * LHID + jb + jj;
                    acc[q][jj] = bih0[r] + bhh0[r] + x0 * Wih0[2 * r] + x1 * Wih0[2 * r + 1];
                }
            if (t > 0) accum_mat(acc, Whh0, h0[trk], jb);   // h0 == 0 at t=0

            float hn[8];
            #pragma unroll
            for (int jj = 0; jj < 8; ++jj) {
                const float iv = sigf(acc[0][jj]);
                const float fv = sigf(acc[1][jj]);
                const float gv = tanhf(acc[2][jj]);
                const float ov = sigf(acc[3][jj]);
                c0r[jj] = fv * c0r[jj] + iv * gv;
                hn[jj]  = ov * tanhf(c0r[jj]);
            }
            __syncthreads();
            #pragma unroll
            for (int jj = 0; jj < 8; ++jj) h0[trk][jb + jj] = hn[jj];
            __syncthreads();
        }

        // ---------- layer 1: x = new h0 ----------
        {
            #pragma unroll
            for (int q = 0; q < 4; ++q)
                #pragma unroll
                for (int jj = 0; jj < 8; ++jj) {
                    const int r = q * LHID + jb + jj;
                    acc[q][jj] = bih1[r] + bhh1[r];
                }
            accum_mat(acc, Wih1, h0[trk], jb);
            if (t > 0) accum_mat(acc, Whh1, h1[trk], jb);   // h1 == 0 at t=0

            float hn[8];
            #pragma unroll
            for (int jj = 0; jj < 8; ++jj) {
                const float iv = sigf(acc[0][jj]);
                const float fv = sigf(acc[1][jj]);
                const float gv = tanhf(acc[2][jj]);
                const float ov = sigf(acc[3][jj]);
                c1r[jj] = fv * c1r[jj] + iv * gv;
                hn[jj]  = ov * tanhf(c1r[jj]);
            }
            __syncthreads();
            #pragma unroll
            for (int jj = 0; jj < 8; ++jj) h1[trk][jb + jj] = hn[jj];
            __syncthreads();
        }
    }

    // ---------- MLP layer 0: mh = relu([f3, h1] @ w0^T + b0) ----------
    // thread: track tl2 = tid>>4, 16 neurons starting at nb2 = (tid&15)*16
    {
        const int tl2 = tid >> 4;
        const int nb2 = (tid & 15) << 4;
        float a[16];
        #pragma unroll
        for (int nn = 0; nn < 16; ++nn) {
            const float* wr = w0p + (size_t)(nb2 + nn) * W0PAD;
            a[nn] = b0[nb2 + nn] + f3[tl2][0] * wr[1] + f3[tl2][1] * wr[2] + f3[tl2][2] * wr[3];
        }
        for (int k = 0; k < LHID; k += 4) {
            const float4 hv = *(const float4*)&h1[tl2][k];
            #pragma unroll
            for (int nn = 0; nn < 16; ++nn) {
                const float4 w = *(const float4*)&w0p[(size_t)(nb2 + nn) * W0PAD + 4 + k];
                a[nn] += hv.x * w.x + hv.y * w.y + hv.z * w.z + hv.w * w.w;
            }
        }
        #pragma unroll
        for (int nn = 0; nn < 16; ++nn) mh[tl2][nb2 + nn] = fmaxf(a[nn], 0.0f);
    }
    __syncthreads();

    // ---------- MLP layer 1: out = mh @ w1^T + b1 ----------
    {
        const int tl2 = tid >> 4;
        const int nb2 = (tid & 15) << 4;
        float a[16];
        #pragma unroll
        for (int nn = 0; nn < 16; ++nn) a[nn] = b1[nb2 + nn];
        for (int k = 0; k < HID; k += 4) {
            const float4 hv = *(const float4*)&mh[tl2][k];
            #pragma unroll
            for (int nn = 0; nn < 16; ++nn) {
                const float4 w = *(const float4*)&w1[(size_t)(nb2 + nn) * HID + k];
                a[nn] += hv.x * w.x + hv.y * w.y + hv.z * w.z + hv.w * w.w;
            }
        }
        const int ng = base + tl2;
        float* op = out + (size_t)ng * HID + nb2;
        #pragma unroll
        for (int nn = 0; nn < 16; ++nn) op[nn] = a[nn];
    }
}

// pos_encoding + logpt/eta/phi passthrough. One thread per (track, pair m<32).
__global__ __launch_bounds__(TPB)
void pos_kernel(const float* __restrict__ tfeat, float* __restrict__ out)
{
    const int idx = blockIdx.x * TPB + threadIdx.x;   // exactly NTOT*32 threads
    const int m = idx & 31;
    const int n = idx >> 5;
    const int b = n / NTRK, tt = n - b * NTRK;

    const float eta = tfeat[((size_t)(b * 18 + 3)) * NTRK + tt];
    const float phi = tfeat[((size_t)(b * 18 + 4)) * NTRK + tt];

    const float inv = powf(10000.0f, -(float)m * (1.0f / 32.0f));
    const float TWO_PI = 6.28318530717958647692f;
    const float pe = eta * TWO_PI * inv;
    const float pp = phi * TWO_PI * inv;

    float* o1 = out + OUT1_OFF + (size_t)n * (HID / 2);
    o1[2 * m]          = sinf(pe);
    o1[2 * m + 1]      = cosf(pe);
    o1[64 + 2 * m]     = sinf(pp);
    o1[64 + 2 * m + 1] = cosf(pp);

    if (m == 0) {
        out[OUT2_OFF + n] = tfeat[((size_t)(b * 18 + 2)) * NTRK + tt];  // logpt
        out[OUT3_OFF + n] = eta;
        out[OUT4_OFF + n] = phi;
    }
}

extern "C" void kernel_launch(void* const* d_in, const int* in_sizes, int n_in,
                              void* d_out, int out_size, void* d_ws, size_t ws_size,
                              hipStream_t stream)
{
    const float* tfeat = (const float*)d_in[0];
    const float* Wih0  = (const float*)d_in[1];
    const float* Whh0  = (const float*)d_in[2];
    const float* bih0  = (const float*)d_in[3];
    const float* bhh0  = (const float*)d_in[4];
    const float* Wih1  = (const float*)d_in[5];
    const float* Whh1  = (const float*)d_in[6];
    const float* bih1  = (const float*)d_in[7];
    const float* bhh1  = (const float*)d_in[8];
    const float* w0    = (const float*)d_in[9];
    const float* b0    = (const float*)d_in[10];
    const float* w1    = (const float*)d_in[11];
    const float* b1    = (const float*)d_in[12];
    float* out = (float*)d_out;
    float* w0p = (float*)d_ws;   // 256*132 floats = 135168 B

    hipLaunchKernelGGL(padw0_kernel, dim3((HID * W0PAD + TPB - 1) / TPB), dim3(TPB), 0, stream,
                       w0, w0p);
    hipLaunchKernelGGL(lstm_mlp_kernel, dim3(NTOT / BTILE), dim3(TPB), 0, stream,
                       tfeat, Wih0, Whh0, bih0, bhh0, Wih1, Whh1, bih1, bhh1,
                       w0p, b0, w1, b1, out);
    hipLaunchKernelGGL(pos_kernel, dim3((NTOT * 32) / TPB), dim3(TPB), 0, stream,
                       tfeat, out);
}

// Round 2
// 1394.818 us; speedup vs baseline: 35.6284x; 35.6284x over previous
//
#include <hip/hip_runtime.h>
#include <math.h>

// ---------------- problem constants ----------------
#define NTRK   1500
#define BSZ    64
#define NTOT   (NTRK*BSZ)        // 96000 tracks
#define LHID   128
#define TSTEPS 6
#define HID    256

#define TPB    256               // 4 waves
#define MTRK   32                // tracks per block
#define NBLK   (NTOT/MTRK)       // 3000 blocks

// ws layout (in shorts / bf16 elements)
#define WHH0_OFF 0
#define WIH1_OFF 65536
#define WHH1_OFF 131072
#define W0B_OFF  196608          // mlp w0 cols 3..130 -> [256][128]
#define W1B_OFF  229376          // mlp w1 [256][256]
#define WS_SHORTS 294912         // 576 KiB

// output layout (flat fp32, return order)
#define OUT1_OFF ((size_t)NTOT*HID)
#define OUT2_OFF (OUT1_OFF + (size_t)NTOT*(HID/2))
#define OUT3_OFF (OUT2_OFF + (size_t)NTOT)
#define OUT4_OFF (OUT3_OFF + (size_t)NTOT)

typedef __bf16 bf16x8 __attribute__((ext_vector_type(8)));
typedef float  f32x4  __attribute__((ext_vector_type(4)));

__device__ __forceinline__ unsigned short f2b(float f) {
    union { float f; unsigned u; } v; v.f = f;
    return (unsigned short)((v.u + 0x7FFF + ((v.u >> 16) & 1)) >> 16);
}
__device__ __forceinline__ float sigf(float x) { return 1.0f / (1.0f + __expf(-x)); }
__device__ __forceinline__ float tanhfast(float x) {
    float e = __expf(2.0f * x);
    return (e - 1.0f) / (e + 1.0f);
}

// ---------------- prep: fp32 -> bf16 weight repack into ws ----------------
__global__ __launch_bounds__(TPB)
void prep_kernel(const float* __restrict__ Whh0, const float* __restrict__ Wih1,
                 const float* __restrict__ Whh1, const float* __restrict__ w0,
                 const float* __restrict__ w1, unsigned short* __restrict__ ws)
{
    int i = blockIdx.x * TPB + threadIdx.x;
    if (i < 65536)            ws[WHH0_OFF + i] = f2b(Whh0[i]);
    else if (i < 131072)      ws[WIH1_OFF + (i - 65536)]  = f2b(Wih1[i - 65536]);
    else if (i < 196608)      ws[WHH1_OFF + (i - 131072)] = f2b(Whh1[i - 131072]);
    else if (i < 229376) { int j = i - 196608; int n = j >> 7, k = j & 127;
                           ws[W0B_OFF + j] = f2b(w0[n * 131 + 3 + k]); }
    else if (i < WS_SHORTS)   ws[W1B_OFF + (i - 229376)]  = f2b(w1[i - 229376]);
}

// A-layout LDS address (in shorts). K=128 buffers (4 k-steps):
__device__ __forceinline__ int aoff4(int m, int k) {
    return (((m >> 4) * 4 + (k >> 5)) * 64 + ((k >> 3) & 3) * 16 + (m & 15)) * 8 + (k & 7);
}
// K=256 buffer (8 k-steps):
__device__ __forceinline__ int aoff8(int m, int k) {
    return (((m >> 4) * 8 + (k >> 5)) * 64 + ((k >> 3) & 3) * 16 + (m & 15)) * 8 + (k & 7);
}

// acc[mt][ti] += A(hA)·B(Wb) over K=128 for 8 N-tiles rowb[ti] (= n0+col)
__device__ __forceinline__ void accum8(f32x4 (&acc)[2][8],
                                       const unsigned short* __restrict__ Wb,
                                       const unsigned short* hA,
                                       const int (&rowb)[8], int lane, int quad)
{
    #pragma unroll
    for (int kk = 0; kk < 4; ++kk) {
        bf16x8 a0 = *(const bf16x8*)&hA[((0 * 4 + kk) * 64 + lane) * 8];
        bf16x8 a1 = *(const bf16x8*)&hA[((1 * 4 + kk) * 64 + lane) * 8];
        #pragma unroll
        for (int ti = 0; ti < 8; ++ti) {
            bf16x8 b = *(const bf16x8*)&Wb[(size_t)rowb[ti] * 128 + kk * 32 + quad * 8];
            acc[0][ti] = __builtin_amdgcn_mfma_f32_16x16x32_bf16(a0, b, acc[0][ti], 0, 0, 0);
            acc[1][ti] = __builtin_amdgcn_mfma_f32_16x16x32_bf16(a1, b, acc[1][ti], 0, 0, 0);
        }
    }
}

__global__ __launch_bounds__(TPB, 2)
void lstm_mlp_mfma(const float* __restrict__ tfeat,
                   const float* __restrict__ Wih0,
                   const float* __restrict__ bih0, const float* __restrict__ bhh0,
                   const float* __restrict__ bih1, const float* __restrict__ bhh1,
                   const float* __restrict__ w0,  const float* __restrict__ b0,
                   const float* __restrict__ b1,
                   const unsigned short* __restrict__ wsb,
                   float* __restrict__ out)
{
    __shared__ unsigned short hA0[4096];   // h0 in A-layout, 32 trk x 128
    __shared__ unsigned short hA1[4096];   // h1
    __shared__ unsigned short mhA[8192];   // mlp hidden, 32 trk x 256
    __shared__ float xb[MTRK][12];
    __shared__ float f3[MTRK][4];

    const int tid  = threadIdx.x;
    const int w    = tid >> 6;
    const int lane = tid & 63;
    const int col  = lane & 15;
    const int quad = lane >> 4;
    const int base = blockIdx.x * MTRK;

    // ---- stage per-track inputs ----
    for (int idx = tid; idx < MTRK * 12; idx += TPB) {
        int tl = idx & 31, f = idx >> 5;
        int n = base + tl, b = n / NTRK, tt = n - b * NTRK;
        xb[tl][f] = tfeat[(size_t)(b * 18 + 6 + f) * NTRK + tt];
    }
    for (int idx = tid; idx < MTRK * 3; idx += TPB) {
        int tl = idx & 31, f = idx >> 5;
        int n = base + tl, b = n / NTRK, tt = n - b * NTRK;
        f3[tl][f] = tfeat[(size_t)(b * 18 + f) * NTRK + tt];
    }
    __syncthreads();

    const unsigned short* Whh0b = wsb + WHH0_OFF;
    const unsigned short* Wih1b = wsb + WIH1_OFF;
    const unsigned short* Whh1b = wsb + WHH1_OFF;
    const unsigned short* w0b   = wsb + W0B_OFF;
    const unsigned short* w1b   = wsb + W1B_OFF;

    // ---- hoisted per-tile constants (t-invariant) ----
    int   rowg[8];
    float bs0[8], bs1[8], wx0[8], wx1[8];
    #pragma unroll
    for (int ti = 0; ti < 8; ++ti) {
        int g = ti >> 1, p = ti & 1;
        int n = g * 128 + w * 32 + p * 16 + col;
        rowg[ti] = n;
        bs0[ti] = bih0[n] + bhh0[n];
        bs1[ti] = bih1[n] + bhh1[n];
        wx0[ti] = Wih0[2 * n];
        wx1[ti] = Wih0[2 * n + 1];
    }

    f32x4 c0[2][2], c1[2][2];
    #pragma unroll
    for (int mt = 0; mt < 2; ++mt)
        #pragma unroll
        for (int p = 0; p < 2; ++p)
            #pragma unroll
            for (int r = 0; r < 4; ++r) { c0[mt][p][r] = 0.0f; c1[mt][p][r] = 0.0f; }

    for (int t = 0; t < TSTEPS; ++t) {
        f32x4 acc[2][8];

        // ---------- layer 0 ----------
        #pragma unroll
        for (int mt = 0; mt < 2; ++mt)
            #pragma unroll
            for (int ti = 0; ti < 8; ++ti)
                #pragma unroll
                for (int r = 0; r < 4; ++r) {
                    int m = mt * 16 + quad * 4 + r;
                    acc[mt][ti][r] = bs0[ti] + xb[m][2 * t] * wx0[ti] + xb[m][2 * t + 1] * wx1[ti];
                }
        if (t > 0) accum8(acc, Whh0b, hA0, rowg, lane, quad);   // reads old h0
        __syncthreads();                                        // all waves done reading h0
        #pragma unroll
        for (int mt = 0; mt < 2; ++mt)
            #pragma unroll
            for (int p = 0; p < 2; ++p)
                #pragma unroll
                for (int r = 0; r < 4; ++r) {
                    float iv = sigf(acc[mt][0 + p][r]);
                    float fv = sigf(acc[mt][2 + p][r]);
                    float gv = tanhfast(acc[mt][4 + p][r]);
                    float ov = sigf(acc[mt][6 + p][r]);
                    float cn = fv * c0[mt][p][r] + iv * gv;
                    c0[mt][p][r] = cn;
                    int m = mt * 16 + quad * 4 + r;
                    int u = w * 32 + p * 16 + col;
                    hA0[aoff4(m, u)] = f2b(ov * tanhfast(cn));
                }
        __syncthreads();                                        // new h0 visible

        // ---------- layer 1 ----------
        #pragma unroll
        for (int mt = 0; mt < 2; ++mt)
            #pragma unroll
            for (int ti = 0; ti < 8; ++ti)
                #pragma unroll
                for (int r = 0; r < 4; ++r) acc[mt][ti][r] = bs1[ti];
        accum8(acc, Wih1b, hA0, rowg, lane, quad);              // new h0
        if (t > 0) accum8(acc, Whh1b, hA1, rowg, lane, quad);   // old h1
        __syncthreads();                                        // all waves done reading h1
        #pragma unroll
        for (int mt = 0; mt < 2; ++mt)
            #pragma unroll
            for (int p = 0; p < 2; ++p)
                #pragma unroll
                for (int r = 0; r < 4; ++r) {
                    float iv = sigf(acc[mt][0 + p][r]);
                    float fv = sigf(acc[mt][2 + p][r]);
                    float gv = tanhfast(acc[mt][4 + p][r]);
                    float ov = sigf(acc[mt][6 + p][r]);
                    float cn = fv * c1[mt][p][r] + iv * gv;
                    c1[mt][p][r] = cn;
                    int m = mt * 16 + quad * 4 + r;
                    int u = w * 32 + p * 16 + col;
                    hA1[aoff4(m, u)] = f2b(ov * tanhfast(cn));
                }
        __syncthreads();                                        // new h1 visible
    }

    // ---------- MLP layer A: mh = relu([f3, h1] @ w0^T + b0) ----------
    {
        f32x4 am[2][4];
        int rowm[4];
        #pragma unroll
        for (int ti = 0; ti < 4; ++ti) {
            int n = w * 64 + ti * 16 + col;
            rowm[ti] = n;
            float bm  = b0[n];
            float wf0 = w0[n * 131 + 0], wf1 = w0[n * 131 + 1], wf2 = w0[n * 131 + 2];
            #pragma unroll
            for (int mt = 0; mt < 2; ++mt)
                #pragma unroll
                for (int r = 0; r < 4; ++r) {
                    int m = mt * 16 + quad * 4 + r;
                    am[mt][ti][r] = bm + f3[m][0] * wf0 + f3[m][1] * wf1 + f3[m][2] * wf2;
                }
        }
        #pragma unroll
        for (int kk = 0; kk < 4; ++kk) {
            bf16x8 a0 = *(const bf16x8*)&hA1[((0 * 4 + kk) * 64 + lane) * 8];
            bf16x8 a1 = *(const bf16x8*)&hA1[((1 * 4 + kk) * 64 + lane) * 8];
            #pragma unroll
            for (int ti = 0; ti < 4; ++ti) {
                bf16x8 b = *(const bf16x8*)&w0b[(size_t)rowm[ti] * 128 + kk * 32 + quad * 8];
                am[0][ti] = __builtin_amdgcn_mfma_f32_16x16x32_bf16(a0, b, am[0][ti], 0, 0, 0);
                am[1][ti] = __builtin_amdgcn_mfma_f32_16x16x32_bf16(a1, b, am[1][ti], 0, 0, 0);
            }
        }
        #pragma unroll
        for (int mt = 0; mt < 2; ++mt)
            #pragma unroll
            for (int ti = 0; ti < 4; ++ti)
                #pragma unroll
                for (int r = 0; r < 4; ++r) {
                    int m = mt * 16 + quad * 4 + r;
                    int u = w * 64 + ti * 16 + col;
                    mhA[aoff8(m, u)] = f2b(fmaxf(am[mt][ti][r], 0.0f));
                }
        __syncthreads();
    }

    // ---------- MLP layer B: out = mh @ w1^T + b1 ----------
    {
        f32x4 ao[2][4];
        int rowm[4];
        #pragma unroll
        for (int ti = 0; ti < 4; ++ti) {
            int n = w * 64 + ti * 16 + col;
            rowm[ti] = n;
            float bv = b1[n];
            #pragma unroll
            for (int mt = 0; mt < 2; ++mt)
                #pragma unroll
                for (int r = 0; r < 4; ++r) ao[mt][ti][r] = bv;
        }
        #pragma unroll
        for (int kk = 0; kk < 8; ++kk) {
            bf16x8 a0 = *(const bf16x8*)&mhA[((0 * 8 + kk) * 64 + lane) * 8];
            bf16x8 a1 = *(const bf16x8*)&mhA[((1 * 8 + kk) * 64 + lane) * 8];
            #pragma unroll
            for (int ti = 0; ti < 4; ++ti) {
                bf16x8 b = *(const bf16x8*)&w1b[(size_t)rowm[ti] * 256 + kk * 32 + quad * 8];
                ao[0][ti] = __builtin_amdgcn_mfma_f32_16x16x32_bf16(a0, b, ao[0][ti], 0, 0, 0);
                ao[1][ti] = __builtin_amdgcn_mfma_f32_16x16x32_bf16(a1, b, ao[1][ti], 0, 0, 0);
            }
        }
        #pragma unroll
        for (int mt = 0; mt < 2; ++mt)
            #pragma unroll
            for (int ti = 0; ti < 4; ++ti)
                #pragma unroll
                for (int r = 0; r < 4; ++r) {
                    int m = base + mt * 16 + quad * 4 + r;
                    out[(size_t)m * HID + w * 64 + ti * 16 + col] = ao[mt][ti][r];
                }
    }
}

// pos_encoding + logpt/eta/phi passthrough.
__global__ __launch_bounds__(TPB)
void pos_kernel(const float* __restrict__ tfeat, float* __restrict__ out)
{
    const int idx = blockIdx.x * TPB + threadIdx.x;   // NTOT*32 threads
    const int m = idx & 31;
    const int n = idx >> 5;
    const int b = n / NTRK, tt = n - b * NTRK;

    const float eta = tfeat[(size_t)(b * 18 + 3) * NTRK + tt];
    const float phi = tfeat[(size_t)(b * 18 + 4) * NTRK + tt];

    const float inv = powf(10000.0f, -(float)m * (1.0f / 32.0f));
    const float TWO_PI = 6.28318530717958647692f;
    const float pe = eta * TWO_PI * inv;
    const float pp = phi * TWO_PI * inv;

    float* o1 = out + OUT1_OFF + (size_t)n * (HID / 2);
    o1[2 * m]          = sinf(pe);
    o1[2 * m + 1]      = cosf(pe);
    o1[64 + 2 * m]     = sinf(pp);
    o1[64 + 2 * m + 1] = cosf(pp);

    if (m == 0) {
        out[OUT2_OFF + n] = tfeat[(size_t)(b * 18 + 2) * NTRK + tt];  // logpt
        out[OUT3_OFF + n] = eta;
        out[OUT4_OFF + n] = phi;
    }
}

extern "C" void kernel_launch(void* const* d_in, const int* in_sizes, int n_in,
                              void* d_out, int out_size, void* d_ws, size_t ws_size,
                              hipStream_t stream)
{
    const float* tfeat = (const float*)d_in[0];
    const float* Wih0  = (const float*)d_in[1];
    const float* Whh0  = (const float*)d_in[2];
    const float* bih0  = (const float*)d_in[3];
    const float* bhh0  = (const float*)d_in[4];
    const float* Wih1  = (const float*)d_in[5];
    const float* Whh1  = (const float*)d_in[6];
    const float* bih1  = (const float*)d_in[7];
    const float* bhh1  = (const float*)d_in[8];
    const float* w0    = (const float*)d_in[9];
    const float* b0    = (const float*)d_in[10];
    const float* w1    = (const float*)d_in[11];
    const float* b1    = (const float*)d_in[12];
    float* out = (float*)d_out;
    unsigned short* wsb = (unsigned short*)d_ws;  // 576 KiB bf16 weights

    hipLaunchKernelGGL(prep_kernel, dim3((WS_SHORTS + TPB - 1) / TPB), dim3(TPB), 0, stream,
                       Whh0, Wih1, Whh1, w0, w1, wsb);
    hipLaunchKernelGGL(lstm_mlp_mfma, dim3(NBLK), dim3(TPB), 0, stream,
                       tfeat, Wih0, bih0, bhh0, bih1, bhh1, w0, b0, b1, wsb, out);
    hipLaunchKernelGGL(pos_kernel, dim3((NTOT * 32) / TPB), dim3(TPB), 0, stream,
                       tfeat, out);
}

// Round 4
// 1387.975 us; speedup vs baseline: 35.8041x; 1.0049x over previous
//
#include <hip/hip_runtime.h>
#include <math.h>

// ---------------- problem constants ----------------
#define NTRK   1500
#define BSZ    64
#define NTOT   (NTRK*BSZ)        // 96000 tracks
#define LHID   128
#define TSTEPS 6
#define HID    256

#define TPB    256               // 4 waves
#define MTRK   32                // tracks per block
#define NBLK   (NTOT/MTRK)       // 3000 blocks

// ws layout (in shorts / bf16 elements)
#define WHH0_OFF 0
#define WIH1_OFF 65536
#define WHH1_OFF 131072
#define W0B_OFF  196608          // mlp w0 cols 3..130 -> [256][128]
#define W1B_OFF  229376          // mlp w1 [256][256]
#define WS_SHORTS 294912         // 576 KiB

// output layout (flat fp32, return order)
#define OUT1_OFF ((size_t)NTOT*HID)
#define OUT2_OFF (OUT1_OFF + (size_t)NTOT*(HID/2))
#define OUT3_OFF (OUT2_OFF + (size_t)NTOT)
#define OUT4_OFF (OUT3_OFF + (size_t)NTOT)

typedef __bf16 bf16x8 __attribute__((ext_vector_type(8)));
typedef float  f32x4  __attribute__((ext_vector_type(4)));

__device__ __forceinline__ unsigned short f2b(float f) {
    union { float f; unsigned u; } v; v.f = f;
    return (unsigned short)((v.u + 0x7FFF + ((v.u >> 16) & 1)) >> 16);
}
__device__ __forceinline__ float sigf(float x) { return 1.0f / (1.0f + __expf(-x)); }
__device__ __forceinline__ float tanhfast(float x) {
    float e = __expf(2.0f * x);
    return (e - 1.0f) / (e + 1.0f);
}

// ---------------- prep: fp32 -> bf16 weight repack into ws ----------------
// NORMAL (cached) stores — we want these resident in L2/L3.
__global__ __launch_bounds__(TPB)
void prep_kernel(const float* __restrict__ Whh0, const float* __restrict__ Wih1,
                 const float* __restrict__ Whh1, const float* __restrict__ w0,
                 const float* __restrict__ w1, unsigned short* __restrict__ ws)
{
    int i = blockIdx.x * TPB + threadIdx.x;
    if (i < 65536)            ws[WHH0_OFF + i] = f2b(Whh0[i]);
    else if (i < 131072)      ws[WIH1_OFF + (i - 65536)]  = f2b(Wih1[i - 65536]);
    else if (i < 196608)      ws[WHH1_OFF + (i - 131072)] = f2b(Whh1[i - 131072]);
    else if (i < 229376) { int j = i - 196608; int n = j >> 7, k = j & 127;
                           ws[W0B_OFF + j] = f2b(w0[n * 131 + 3 + k]); }
    else if (i < WS_SHORTS)   ws[W1B_OFF + (i - 229376)]  = f2b(w1[i - 229376]);
}

// A-layout LDS address (in shorts). K=128 buffers (4 k-steps):
__device__ __forceinline__ int aoff4(int m, int k) {
    return (((m >> 4) * 4 + (k >> 5)) * 64 + ((k >> 3) & 3) * 16 + (m & 15)) * 8 + (k & 7);
}

// acc[mt][ti] += A(hA)·B(Wb) over K=128 for 8 N-tiles rowb[ti]
__device__ __forceinline__ void accum8(f32x4 (&acc)[2][8],
                                       const unsigned short* __restrict__ Wb,
                                       const unsigned short* hA,
                                       const int (&rowb)[8], int lane, int quad)
{
    #pragma unroll
    for (int kk = 0; kk < 4; ++kk) {
        bf16x8 a0 = *(const bf16x8*)&hA[((0 * 4 + kk) * 64 + lane) * 8];
        bf16x8 a1 = *(const bf16x8*)&hA[((1 * 4 + kk) * 64 + lane) * 8];
        #pragma unroll
        for (int ti = 0; ti < 8; ++ti) {
            bf16x8 b = *(const bf16x8*)&Wb[(size_t)rowb[ti] * 128 + kk * 32 + quad * 8];
            acc[0][ti] = __builtin_amdgcn_mfma_f32_16x16x32_bf16(a0, b, acc[0][ti], 0, 0, 0);
            acc[1][ti] = __builtin_amdgcn_mfma_f32_16x16x32_bf16(a1, b, acc[1][ti], 0, 0, 0);
        }
    }
}

__global__ __launch_bounds__(TPB, 2)
void lstm_mlp_mfma(const float* __restrict__ tfeat,
                   const float* __restrict__ Wih0,
                   const float* __restrict__ bih0, const float* __restrict__ bhh0,
                   const float* __restrict__ bih1, const float* __restrict__ bhh1,
                   const float* __restrict__ w0,  const float* __restrict__ b0,
                   const float* __restrict__ b1,
                   const unsigned short* __restrict__ wsb,
                   float* __restrict__ out)
{
    // Manual LDS layout so the epilogue can alias the dead h/mh buffers.
    __shared__ __align__(16) char smem[34816];
    unsigned short* hA0 = (unsigned short*)smem;            // [0,8192)   h0 A-layout
    unsigned short* hA1 = (unsigned short*)(smem + 8192);   // [8192,16384)
    unsigned short* mhA = (unsigned short*)(smem + 16384);  // [16384,32768) mlp hidden
    float (*xb)[12] = (float(*)[12])(smem + 32768);         // [32768,34304)
    float (*f3)[4]  = (float(*)[4])(smem + 34304);          // [34304,34816)
    float* outb = (float*)smem;                             // epilogue alias, stride 260

    const int tid  = threadIdx.x;
    const int w    = tid >> 6;
    const int lane = tid & 63;
    const int col  = lane & 15;
    const int quad = lane >> 4;
    const int base = blockIdx.x * MTRK;

    // ---- stage per-track inputs ----
    for (int idx = tid; idx < MTRK * 12; idx += TPB) {
        int tl = idx & 31, f = idx >> 5;
        int n = base + tl, b = n / NTRK, tt = n - b * NTRK;
        xb[tl][f] = tfeat[(size_t)(b * 18 + 6 + f) * NTRK + tt];
    }
    for (int idx = tid; idx < MTRK * 3; idx += TPB) {
        int tl = idx & 31, f = idx >> 5;
        int n = base + tl, b = n / NTRK, tt = n - b * NTRK;
        f3[tl][f] = tfeat[(size_t)(b * 18 + f) * NTRK + tt];
    }
    __syncthreads();

    const unsigned short* Whh0b = wsb + WHH0_OFF;
    const unsigned short* Wih1b = wsb + WIH1_OFF;
    const unsigned short* Whh1b = wsb + WHH1_OFF;
    const unsigned short* w0b   = wsb + W0B_OFF;
    const unsigned short* w1b   = wsb + W1B_OFF;

    // ---- hoisted per-tile constants (t-invariant) ----
    int   rowg[8];
    float bs0[8], bs1[8], wx0[8], wx1[8];
    #pragma unroll
    for (int ti = 0; ti < 8; ++ti) {
        int g = ti >> 1, p = ti & 1;
        int n = g * 128 + w * 32 + p * 16 + col;
        rowg[ti] = n;
        bs0[ti] = bih0[n] + bhh0[n];
        bs1[ti] = bih1[n] + bhh1[n];
        wx0[ti] = Wih0[2 * n];
        wx1[ti] = Wih0[2 * n + 1];
    }

    f32x4 c0[2][2], c1[2][2];
    #pragma unroll
    for (int mt = 0; mt < 2; ++mt)
        #pragma unroll
        for (int p = 0; p < 2; ++p)
            #pragma unroll
            for (int r = 0; r < 4; ++r) { c0[mt][p][r] = 0.0f; c1[mt][p][r] = 0.0f; }

    for (int t = 0; t < TSTEPS; ++t) {
        f32x4 acc[2][8];

        // ---------- layer 0 ----------
        #pragma unroll
        for (int mt = 0; mt < 2; ++mt)
            #pragma unroll
            for (int ti = 0; ti < 8; ++ti)
                #pragma unroll
                for (int r = 0; r < 4; ++r) {
                    int m = mt * 16 + quad * 4 + r;
                    acc[mt][ti][r] = bs0[ti] + xb[m][2 * t] * wx0[ti] + xb[m][2 * t + 1] * wx1[ti];
                }
        if (t > 0) accum8(acc, Whh0b, hA0, rowg, lane, quad);   // reads old h0
        __syncthreads();
        #pragma unroll
        for (int mt = 0; mt < 2; ++mt)
            #pragma unroll
            for (int p = 0; p < 2; ++p)
                #pragma unroll
                for (int r = 0; r < 4; ++r) {
                    float iv = sigf(acc[mt][0 + p][r]);
                    float fv = sigf(acc[mt][2 + p][r]);
                    float gv = tanhfast(acc[mt][4 + p][r]);
                    float ov = sigf(acc[mt][6 + p][r]);
                    float cn = fv * c0[mt][p][r] + iv * gv;
                    c0[mt][p][r] = cn;
                    int m = mt * 16 + quad * 4 + r;
                    int u = w * 32 + p * 16 + col;
                    hA0[aoff4(m, u)] = f2b(ov * tanhfast(cn));
                }
        __syncthreads();

        // ---------- layer 1 ----------
        #pragma unroll
        for (int mt = 0; mt < 2; ++mt)
            #pragma unroll
            for (int ti = 0; ti < 8; ++ti)
                #pragma unroll
                for (int r = 0; r < 4; ++r) acc[mt][ti][r] = bs1[ti];
        accum8(acc, Wih1b, hA0, rowg, lane, quad);              // new h0
        if (t > 0) accum8(acc, Whh1b, hA1, rowg, lane, quad);   // old h1
        __syncthreads();
        #pragma unroll
        for (int mt = 0; mt < 2; ++mt)
            #pragma unroll
            for (int p = 0; p < 2; ++p)
                #pragma unroll
                for (int r = 0; r < 4; ++r) {
                    float iv = sigf(acc[mt][0 + p][r]);
                    float fv = sigf(acc[mt][2 + p][r]);
                    float gv = tanhfast(acc[mt][4 + p][r]);
                    float ov = sigf(acc[mt][6 + p][r]);
                    float cn = fv * c1[mt][p][r] + iv * gv;
                    c1[mt][p][r] = cn;
                    int m = mt * 16 + quad * 4 + r;
                    int u = w * 32 + p * 16 + col;
                    hA1[aoff4(m, u)] = f2b(ov * tanhfast(cn));
                }
        __syncthreads();
    }

    // ---------- MLP layer A: mh = relu([f3, h1] @ w0^T + b0) ----------
    {
        f32x4 am[2][4];
        int rowm[4];
        #pragma unroll
        for (int ti = 0; ti < 4; ++ti) {
            int n = w * 64 + ti * 16 + col;
            rowm[ti] = n;
            float bm  = b0[n];
            float wf0 = w0[n * 131 + 0], wf1 = w0[n * 131 + 1], wf2 = w0[n * 131 + 2];
            #pragma unroll
            for (int mt = 0; mt < 2; ++mt)
                #pragma unroll
                for (int r = 0; r < 4; ++r) {
                    int m = mt * 16 + quad * 4 + r;
                    am[mt][ti][r] = bm + f3[m][0] * wf0 + f3[m][1] * wf1 + f3[m][2] * wf2;
                }
        }
        #pragma unroll
        for (int kk = 0; kk < 4; ++kk) {
            bf16x8 a0 = *(const bf16x8*)&hA1[((0 * 4 + kk) * 64 + lane) * 8];
            bf16x8 a1 = *(const bf16x8*)&hA1[((1 * 4 + kk) * 64 + lane) * 8];
            #pragma unroll
            for (int ti = 0; ti < 4; ++ti) {
                bf16x8 b = *(const bf16x8*)&w0b[(size_t)rowm[ti] * 128 + kk * 32 + quad * 8];
                am[0][ti] = __builtin_amdgcn_mfma_f32_16x16x32_bf16(a0, b, am[0][ti], 0, 0, 0);
                am[1][ti] = __builtin_amdgcn_mfma_f32_16x16x32_bf16(a1, b, am[1][ti], 0, 0, 0);
            }
        }
        // mh A-layout (K=256 -> 8 k-steps)
        #pragma unroll
        for (int mt = 0; mt < 2; ++mt)
            #pragma unroll
            for (int ti = 0; ti < 4; ++ti)
                #pragma unroll
                for (int r = 0; r < 4; ++r) {
                    int m = mt * 16 + quad * 4 + r;
                    int u = w * 64 + ti * 16 + col;
                    int off = (((m >> 4) * 8 + (u >> 5)) * 64 + ((u >> 3) & 3) * 16 + (m & 15)) * 8 + (u & 7);
                    mhA[off] = f2b(fmaxf(am[mt][ti][r], 0.0f));
                }
        __syncthreads();
    }

    // ---------- MLP layer B: out = mh @ w1^T + b1 ----------
    {
        f32x4 ao[2][4];
        int rowm[4];
        #pragma unroll
        for (int ti = 0; ti < 4; ++ti) {
            int n = w * 64 + ti * 16 + col;
            rowm[ti] = n;
            float bv = b1[n];
            #pragma unroll
            for (int mt = 0; mt < 2; ++mt)
                #pragma unroll
                for (int r = 0; r < 4; ++r) ao[mt][ti][r] = bv;
        }
        #pragma unroll
        for (int kk = 0; kk < 8; ++kk) {
            bf16x8 a0 = *(const bf16x8*)&mhA[((0 * 8 + kk) * 64 + lane) * 8];
            bf16x8 a1 = *(const bf16x8*)&mhA[((1 * 8 + kk) * 64 + lane) * 8];
            #pragma unroll
            for (int ti = 0; ti < 4; ++ti) {
                bf16x8 b = *(const bf16x8*)&w1b[(size_t)rowm[ti] * 256 + kk * 32 + quad * 8];
                ao[0][ti] = __builtin_amdgcn_mfma_f32_16x16x32_bf16(a0, b, ao[0][ti], 0, 0, 0);
                ao[1][ti] = __builtin_amdgcn_mfma_f32_16x16x32_bf16(a1, b, ao[1][ti], 0, 0, 0);
            }
        }
        __syncthreads();   // all mhA reads complete; LDS now reusable as outb

        // stage in LDS (stride 260 floats -> 2-way-max bank aliasing on writes)
        #pragma unroll
        for (int mt = 0; mt < 2; ++mt)
            #pragma unroll
            for (int ti = 0; ti < 4; ++ti)
                #pragma unroll
                for (int r = 0; r < 4; ++r)
                    outb[(mt * 16 + quad * 4 + r) * 260 + w * 64 + ti * 16 + col] = ao[mt][ti][r];
        __syncthreads();

        // fully-coalesced nontemporal stores: 16 B/lane, 1 KiB/wave-inst
        for (int i = tid; i < MTRK * 64; i += TPB) {
            int row = i >> 6, c4 = (i & 63) << 2;
            f32x4 v = *(const f32x4*)&outb[row * 260 + c4];
            __builtin_nontemporal_store(v, (f32x4*)(out + (size_t)(base + row) * HID + c4));
        }
    }
}

// pos_encoding + logpt/eta/phi passthrough.
__global__ __launch_bounds__(TPB)
void pos_kernel(const float* __restrict__ tfeat, float* __restrict__ out)
{
    const int idx = blockIdx.x * TPB + threadIdx.x;   // NTOT*32 threads
    const int m = idx & 31;
    const int n = idx >> 5;
    const int b = n / NTRK, tt = n - b * NTRK;

    const float eta = tfeat[(size_t)(b * 18 + 3) * NTRK + tt];
    const float phi = tfeat[(size_t)(b * 18 + 4) * NTRK + tt];

    // 10000^(-m/32) = exp2(-m * log2(10000)/32)
    const float inv = exp2f(-(float)m * (13.28771237954945f / 32.0f));
    const float TWO_PI = 6.28318530717958647692f;
    const float pe = eta * TWO_PI * inv;
    const float pp = phi * TWO_PI * inv;

    float* o1 = out + OUT1_OFF + (size_t)n * (HID / 2);
    __builtin_nontemporal_store(sinf(pe), o1 + 2 * m);
    __builtin_nontemporal_store(cosf(pe), o1 + 2 * m + 1);
    __builtin_nontemporal_store(sinf(pp), o1 + 64 + 2 * m);
    __builtin_nontemporal_store(cosf(pp), o1 + 64 + 2 * m + 1);

    if (m == 0) {
        __builtin_nontemporal_store(tfeat[(size_t)(b * 18 + 2) * NTRK + tt], out + OUT2_OFF + n);
        __builtin_nontemporal_store(eta, out + OUT3_OFF + n);
        __builtin_nontemporal_store(phi, out + OUT4_OFF + n);
    }
}

extern "C" void kernel_launch(void* const* d_in, const int* in_sizes, int n_in,
                              void* d_out, int out_size, void* d_ws, size_t ws_size,
                              hipStream_t stream)
{
    const float* tfeat = (const float*)d_in[0];
    const float* Wih0  = (const float*)d_in[1];
    const float* Whh0  = (const float*)d_in[2];
    const float* bih0  = (const float*)d_in[3];
    const float* bhh0  = (const float*)d_in[4];
    const float* Wih1  = (const float*)d_in[5];
    const float* Whh1  = (const float*)d_in[6];
    const float* bih1  = (const float*)d_in[7];
    const float* bhh1  = (const float*)d_in[8];
    const float* w0    = (const float*)d_in[9];
    const float* b0    = (const float*)d_in[10];
    const float* w1    = (const float*)d_in[11];
    const float* b1    = (const float*)d_in[12];
    float* out = (float*)d_out;
    unsigned short* wsb = (unsigned short*)d_ws;  // 576 KiB bf16 weights

    hipLaunchKernelGGL(prep_kernel, dim3((WS_SHORTS + TPB - 1) / TPB), dim3(TPB), 0, stream,
                       Whh0, Wih1, Whh1, w0, w1, wsb);
    hipLaunchKernelGGL(lstm_mlp_mfma, dim3(NBLK), dim3(TPB), 0, stream,
                       tfeat, Wih0, bih0, bhh0, bih1, bhh1, w0, b0, b1, wsb, out);
    hipLaunchKernelGGL(pos_kernel, dim3((NTOT * 32) / TPB), dim3(TPB), 0, stream,
                       tfeat, out);
}